// Round 3
// baseline (82.040 us; speedup 1.0000x reference)
//
#include <hip/hip_runtime.h>
#include <math.h>

// Problem constants
#define BB 128
#define ND 32
#define NIJ 16384
#define EPS2 0.25f
#define EPS4 0.0625f

// Tiling: 256 blocks x 64 ij, full batch per block.
// 1024 thr: lane map gij[0-2] nq[3-4] bl[5-9].
// Each thread: 4 b (bl+32*rb) x 8 ij (gij+8*it) x 8 n (nq*8..+8).
// Data regs: x 4x8 + num 4x8 = 64; coef transient 8 float4 = 32 -> fits 128 cap.
#define TIJ 64
#define NBLK (NIJ / TIJ)        // 256 (1/CU)
#define NTHR 1024
#define ROWF 132                // coef row: cA32|cB32|K32|KV32|pad4

// LDS layout (floats)
#define XS_OFF  8448            // X stage [128][36]
#define CC_OFF  13056
#define LAM_OFF 13120
#define LDS_FL  13184           // 52.7 KB
#define STG_ROW 36

// part layout per block (packed): num[128][32] @0, den[128] @4096
#define PART_STRIDE 4224
#define DEN_OFF_P 4096

__global__ __launch_bounds__(NTHR, 4) void gmm_fused(
    const float* __restrict__ Xg,
    const float* __restrict__ tptr,
    const float* __restrict__ Mu0, const float* __restrict__ Mu1,
    const float* __restrict__ S0,  const float* __restrict__ S1,
    const float* __restrict__ Lam,
    float* __restrict__ part)
{
    __shared__ __align__(16) float lds[LDS_FL];

    const int tid  = threadIdx.x;
    const int blk  = blockIdx.x;
    const int ij0g = blk * TIJ;
    const float t   = tptr[0];
    const float omt = 1.0f - t;

    // ---- Phase 1a: X full batch -> LDS stage [128][36], 1 float4/thread ----
    {
        const int r  = tid >> 3;           // 0..127
        const int c4 = (tid & 7) * 4;      // 0..28
        *(float4*)&lds[XS_OFF + r * STG_ROW + c4] =
            *(const float4*)&Xg[tid * 4];
    }

    // ---- Phase 1b: per-(ij, n) coefficients into LDS (each exactly once) ----
    // 64 ij * 32 n = 2048 pairs over 1024 threads -> 2 each
#pragma unroll
    for (int k = 0; k < (TIJ * ND) / NTHR; ++k) {
        const int idx = tid + k * NTHR;
        const int ijl = idx >> 5;          // 0..63
        const int n   = idx & 31;
        const int ij  = ij0g + ijl;
        const int i   = ij >> 7;
        const int j   = ij & 127;
        const float s0  = S0[i * ND + n];
        const float s1  = S1[j * ND + n];
        const float mu0 = Mu0[i * ND + n];
        const float mu1 = Mu1[j * ND + n];
        const float Ds  = sqrtf(4.0f * s0 * s1 + EPS4);
        const float Cs  = 0.5f * (Ds - EPS2);
        const float Sigma = omt * omt * s0 + t * t * s1
                          + 2.0f * t * omt * Cs + EPS2 * t * omt;
        const float St  = (t * s1 + omt * Cs) - (omt * s0 + t * Cs) - EPS2 * t;
        const float Mut = omt * mu0 + t * mu1;
        const float v   = mu1 - mu0;
        const float invS = 1.0f / Sigma;
        const float Kf  = St * invS;
        const float cA  = -0.5f * invS;
        const float cB  = Mut * invS;
        lds[ijl * ROWF + n]      = cA;
        lds[ijl * ROWF + 32 + n] = cB;
        lds[ijl * ROWF + 64 + n] = Kf;
        lds[ijl * ROWF + 96 + n] = v - Kf * Mut;
        float cc = cA * Mut * Mut - 0.5f * __logf(Sigma);
        cc += __shfl_xor(cc, 1);
        cc += __shfl_xor(cc, 2);
        cc += __shfl_xor(cc, 4);
        cc += __shfl_xor(cc, 8);
        cc += __shfl_xor(cc, 16);
        if (n == 0) lds[CC_OFF + ijl] = cc;
    }
    if (tid < TIJ) lds[LAM_OFF + tid] = Lam[ij0g + tid];

    __syncthreads();

    // ---- Thread mapping: 4 b x 8 ij x 8 n ----
    const int gij = tid & 7;          // lane bits 0-2: ij within group
    const int nq  = (tid >> 3) & 3;   // lane bits 3-4: n-quarter
    const int bl  = tid >> 5;         // 0..31 -> b in {bl, bl+32, bl+64, bl+96}
    const int n0  = nq * 8;

    // X quarter-rows -> registers
    float x[4][8];
#pragma unroll
    for (int rb = 0; rb < 4; ++rb) {
        const float4 v4 = *(const float4*)&lds[XS_OFF + (bl + 32 * rb) * STG_ROW + n0];
        const float4 w4 = *(const float4*)&lds[XS_OFF + (bl + 32 * rb) * STG_ROW + n0 + 4];
        x[rb][0] = v4.x; x[rb][1] = v4.y; x[rb][2] = v4.z; x[rb][3] = v4.w;
        x[rb][4] = w4.x; x[rb][5] = w4.y; x[rb][6] = w4.z; x[rb][7] = w4.w;
    }

    float num[4][8];
#pragma unroll
    for (int rb = 0; rb < 4; ++rb)
#pragma unroll
        for (int n = 0; n < 8; ++n) num[rb][n] = 0.0f;
    float den[4] = {0.0f, 0.0f, 0.0f, 0.0f};

    // ---- Phase 2: 8 iters; coef quarter-row shared by 4 b ----
#pragma unroll
    for (int it = 0; it < TIJ / 8; ++it) {
        const int ijl = gij + (it << 3);
        const float* __restrict__ row = &lds[ijl * ROWF + n0];
        const float4 a0 = *(const float4*)&row[0];
        const float4 a1 = *(const float4*)&row[4];
        const float4 b0 = *(const float4*)&row[32];
        const float4 b1 = *(const float4*)&row[36];

        // 8 independent logw chains (2 per rb, 4 deep each)
        float la[4], lb[4];
#pragma unroll
        for (int rb = 0; rb < 4; ++rb) {
            float u = fmaf(fmaf(a0.x, x[rb][0], b0.x), x[rb][0], 0.0f);
            float v = fmaf(fmaf(a0.y, x[rb][1], b0.y), x[rb][1], 0.0f);
            u = fmaf(fmaf(a0.z, x[rb][2], b0.z), x[rb][2], u);
            v = fmaf(fmaf(a0.w, x[rb][3], b0.w), x[rb][3], v);
            u = fmaf(fmaf(a1.x, x[rb][4], b1.x), x[rb][4], u);
            v = fmaf(fmaf(a1.y, x[rb][5], b1.y), x[rb][5], v);
            u = fmaf(fmaf(a1.z, x[rb][6], b1.z), x[rb][6], u);
            v = fmaf(fmaf(a1.w, x[rb][7], b1.w), x[rb][7], v);
            la[rb] = u; lb[rb] = v;
        }

        // issue num-coef loads early; latency hidden under fold+exp
        const float4 k0 = *(const float4*)&row[64];
        const float4 k1 = *(const float4*)&row[68];
        const float4 v0 = *(const float4*)&row[96];
        const float4 v1 = *(const float4*)&row[100];
        const float cc0 = lds[CC_OFF + ijl];
        const float lam = lds[LAM_OFF + ijl];

        float w[4];
#pragma unroll
        for (int rb = 0; rb < 4; ++rb) {
            float lw = la[rb] + lb[rb];
            lw += __shfl_xor(lw, 8);       // fold nq bit 0
            lw += __shfl_xor(lw, 16);      // fold nq bit 1
            lw = fminf(fmaxf(lw + cc0, -50.0f), 50.0f);
            w[rb] = __expf(lw) * lam;
            den[rb] += w[rb];
        }

#pragma unroll
        for (int rb = 0; rb < 4; ++rb) {
            num[rb][0] = fmaf(w[rb], fmaf(k0.x, x[rb][0], v0.x), num[rb][0]);
            num[rb][1] = fmaf(w[rb], fmaf(k0.y, x[rb][1], v0.y), num[rb][1]);
            num[rb][2] = fmaf(w[rb], fmaf(k0.z, x[rb][2], v0.z), num[rb][2]);
            num[rb][3] = fmaf(w[rb], fmaf(k0.w, x[rb][3], v0.w), num[rb][3]);
            num[rb][4] = fmaf(w[rb], fmaf(k1.x, x[rb][4], v1.x), num[rb][4]);
            num[rb][5] = fmaf(w[rb], fmaf(k1.y, x[rb][5], v1.y), num[rb][5]);
            num[rb][6] = fmaf(w[rb], fmaf(k1.z, x[rb][6], v1.z), num[rb][6]);
            num[rb][7] = fmaf(w[rb], fmaf(k1.w, x[rb][7], v1.w), num[rb][7]);
        }
    }

    // ---- Fold-reduce across the 8 gij lanes: 8 cols -> 1 col/lane ----
    // End state: lane gij holds column gij of its quarter.
#pragma unroll
    for (int rb = 0; rb < 4; ++rb) {
#pragma unroll
        for (int c = 0; c < 4; ++c) {      // mask 4: 8 -> 4
            const float s = (gij & 4) ? num[rb][c] : num[rb][c + 4];
            const float r = __shfl_xor(s, 4);
            num[rb][c] = ((gij & 4) ? num[rb][c + 4] : num[rb][c]) + r;
        }
#pragma unroll
        for (int c = 0; c < 2; ++c) {      // mask 2: 4 -> 2
            const float s = (gij & 2) ? num[rb][c] : num[rb][c + 2];
            const float r = __shfl_xor(s, 2);
            num[rb][c] = ((gij & 2) ? num[rb][c + 2] : num[rb][c]) + r;
        }
        {                                   // mask 1: 2 -> 1
            const float s = (gij & 1) ? num[rb][0] : num[rb][1];
            const float r = __shfl_xor(s, 1);
            num[rb][0] = ((gij & 1) ? num[rb][1] : num[rb][0]) + r;
        }
        den[rb] += __shfl_xor(den[rb], 1);
        den[rb] += __shfl_xor(den[rb], 2);
        den[rb] += __shfl_xor(den[rb], 4);
    }

    // ---- Direct coalesced global store ----
    // Lane (gij, nq) holds col nq*8+gij = tid&31: wave covers 2 b x 32 cols
    // = 256 B contiguous per scalar store.
    float* __restrict__ dstg = part + (size_t)blk * PART_STRIDE;
    const int col = (tid & 31);
#pragma unroll
    for (int rb = 0; rb < 4; ++rb) {
        dstg[(bl + 32 * rb) * 32 + col] = num[rb][0];
    }
    if (col == 0) {
#pragma unroll
        for (int rb = 0; rb < 4; ++rb) {
            dstg[DEN_OFF_P + bl + 32 * rb] = den[rb];
        }
    }
}

// 256 blocks = (b, n-half). Thread (sg, n16): sums 16 slices; LDS combine.
__global__ __launch_bounds__(256) void gmm_reduce(
    const float* __restrict__ part,
    float* __restrict__ out)
{
    const int blk = blockIdx.x;            // 0..255
    const int b   = blk >> 1;
    const int nh  = blk & 1;
    const int tid = threadIdx.x;
    const int n16 = tid & 15;
    const int sg  = tid >> 4;              // 0..15 slice-groups
    const int n   = nh * 16 + n16;

    float num = 0.0f, den = 0.0f;
#pragma unroll
    for (int g = 0; g < 16; ++g) {
        const int s = sg + g * 16;         // slice 0..255
        const size_t base = (size_t)s * PART_STRIDE;
        num += part[base + b * 32 + n];
        den += part[base + DEN_OFF_P + b]; // same addr across n16 -> broadcast
    }

    __shared__ float red[16][18];
    red[sg][n16] = num;
    if (n16 == 0) red[sg][16] = den;
    __syncthreads();

    if (tid < 16) {
        float ns = 0.0f, ds = 0.0f;
#pragma unroll
        for (int k = 0; k < 16; ++k) {
            ns += red[k][tid];
            ds += red[k][16];
        }
        out[b * 32 + nh * 16 + tid] = ns / ds;
    }
}

extern "C" void kernel_launch(void* const* d_in, const int* in_sizes, int n_in,
                              void* d_out, int out_size, void* d_ws, size_t ws_size,
                              hipStream_t stream)
{
    const float* X   = (const float*)d_in[0];
    const float* t   = (const float*)d_in[1];
    const float* Mu0 = (const float*)d_in[2];
    const float* Mu1 = (const float*)d_in[3];
    const float* S0  = (const float*)d_in[4];
    const float* S1  = (const float*)d_in[5];
    const float* Lam = (const float*)d_in[6];
    float* out  = (float*)d_out;
    float* part = (float*)d_ws;             // NBLK * PART_STRIDE floats (4.3 MB)

    gmm_fused<<<NBLK, NTHR, 0, stream>>>(X, t, Mu0, Mu1, S0, S1, Lam, part);
    gmm_reduce<<<2 * BB, 256, 0, stream>>>(part, out);
}